// Round 1
// baseline (2556.574 us; speedup 1.0000x reference)
//
#include <hip/hip_runtime.h>
#include <hip/hip_bf16.h>

typedef _Float16 h16;
typedef _Float16 f16x8 __attribute__((ext_vector_type(8)));
typedef _Float16 f16x4 __attribute__((ext_vector_type(4)));
typedef float f32x4 __attribute__((ext_vector_type(4)));

#define SEGS 32
#define LCTX 512
#define RQ 64
#define NH 32
#define HDIM 128
#define DMODEL 4096

// ---------------- cast fp32 -> fp16 (row-major preserved) ----------------
__global__ __launch_bounds__(256) void cast_f16_kernel(const float* __restrict__ in,
                                                       h16* __restrict__ out) {
    long i = ((long)blockIdx.x * 256 + threadIdx.x) * 4;
    float4 f = *(const float4*)&in[i];
    f16x4 o;
    o[0] = (h16)f.x; o[1] = (h16)f.y; o[2] = (h16)f.z; o[3] = (h16)f.w;
    *(f16x4*)&out[i] = o;
}

// ---------------- transpose + cast: in[K][N] fp32 -> out[N][K] fp16 ----------------
__global__ __launch_bounds__(256) void transpose_cast_kernel(const float* __restrict__ in,
                                                             h16* __restrict__ out,
                                                             int K, int N) {
    __shared__ float tile[32][33];
    int bx = blockIdx.x;  // tiles along N
    int by = blockIdx.y;  // tiles along K
    int tx = threadIdx.x & 31, ty = threadIdx.x >> 5;  // ty 0..7
#pragma unroll
    for (int j = 0; j < 4; j++)
        tile[ty + j * 8][tx] = in[(long)(by * 32 + ty + j * 8) * N + bx * 32 + tx];
    __syncthreads();
#pragma unroll
    for (int j = 0; j < 4; j++)
        out[(long)(bx * 32 + ty + j * 8) * K + by * 32 + tx] = (h16)tile[tx][ty + j * 8];
}

// ---------------- pooling (mean of 8 rows) + rmsnorm -> queries fp32, qn fp16 ----------------
__global__ __launch_bounds__(256) void pool_rms_kernel(const float* __restrict__ x,
                                                       const float* __restrict__ wnorm,
                                                       float* __restrict__ queries,
                                                       h16* __restrict__ qn) {
    const int qi = blockIdx.x;      // 0..2047
    const int t = threadIdx.x;
    const long base = (long)qi * 8 * DMODEL;
    float v[16];
    float ss = 0.f;
#pragma unroll
    for (int i = 0; i < 16; i++) {
        int col = t + i * 256;
        float s = 0.f;
#pragma unroll
        for (int r = 0; r < 8; r++) s += x[base + (long)r * DMODEL + col];
        v[i] = s * 0.125f;
        ss += v[i] * v[i];
    }
#pragma unroll
    for (int d = 1; d < 64; d <<= 1) ss += __shfl_xor(ss, d, 64);
    __shared__ float red[4];
    if ((t & 63) == 0) red[t >> 6] = ss;
    __syncthreads();
    float tot = red[0] + red[1] + red[2] + red[3];
    float scale = rsqrtf(tot / (float)DMODEL + 1e-5f);
#pragma unroll
    for (int i = 0; i < 16; i++) {
        int col = t + i * 256;
        queries[(long)qi * DMODEL + col] = v[i];
        qn[(long)qi * DMODEL + col] = (h16)(v[i] * scale * wnorm[col]);
    }
}

// ---------------- GEMM: C[M][N] = A[M][K] @ Bt[N][K]^T  (fp16 in, MFMA 16x16x32) --------
// EPI==0: write fp16 C.  EPI==1: write fp32 C + res (residual add).
__global__ __launch_bounds__(256) void gemm_bt_kernel(const h16* __restrict__ A,
                                                      const h16* __restrict__ Bt,
                                                      h16* __restrict__ Ch,
                                                      float* __restrict__ Cf,
                                                      const float* __restrict__ res,
                                                      int M, int N, int K, int EPI) {
    __shared__ h16 Als[128][40];  // 32 + 8 pad -> 80B rows (16-aligned, 2-way banks = free)
    __shared__ h16 Bls[128][40];
    const int t = threadIdx.x;
    const int lane = t & 63;
    const int wv = t >> 6;
    const int wm = wv >> 1, wn = wv & 1;
    const int row16 = lane & 15, quad = lane >> 4;
    const int bx = blockIdx.x, by = blockIdx.y;

    f32x4 acc[4][4] = {};

    const int ar = t >> 2;        // 0..63
    const int ac = (t & 3) * 8;   // 0,8,16,24
    const long arow0 = (long)(by * 128 + ar) * K;
    const long arow1 = (long)(by * 128 + ar + 64) * K;
    const long brow0 = (long)(bx * 128 + ar) * K;
    const long brow1 = (long)(bx * 128 + ar + 64) * K;

    for (int k0 = 0; k0 < K; k0 += 32) {
        *(uint4*)&Als[ar][ac]      = *(const uint4*)&A[arow0 + k0 + ac];
        *(uint4*)&Als[ar + 64][ac] = *(const uint4*)&A[arow1 + k0 + ac];
        *(uint4*)&Bls[ar][ac]      = *(const uint4*)&Bt[brow0 + k0 + ac];
        *(uint4*)&Bls[ar + 64][ac] = *(const uint4*)&Bt[brow1 + k0 + ac];
        __syncthreads();
        f16x8 a[4], b[4];
#pragma unroll
        for (int i = 0; i < 4; i++) a[i] = *(const f16x8*)&Als[wm * 64 + i * 16 + row16][quad * 8];
#pragma unroll
        for (int i = 0; i < 4; i++) b[i] = *(const f16x8*)&Bls[wn * 64 + i * 16 + row16][quad * 8];
#pragma unroll
        for (int i = 0; i < 4; i++)
#pragma unroll
            for (int j = 0; j < 4; j++)
                acc[i][j] = __builtin_amdgcn_mfma_f32_16x16x32_f16(a[i], b[j], acc[i][j], 0, 0, 0);
        __syncthreads();
    }
    // epilogue: C/D layout row = quad*4+reg, col = lane&15
#pragma unroll
    for (int i = 0; i < 4; i++) {
        int gr = by * 128 + wm * 64 + i * 16 + quad * 4;
#pragma unroll
        for (int j = 0; j < 4; j++) {
            int gc = bx * 128 + wn * 64 + j * 16 + row16;
#pragma unroll
            for (int r = 0; r < 4; r++) {
                long idx = (long)(gr + r) * N + gc;
                float v = acc[i][j][r];
                if (EPI == 0) Ch[idx] = (h16)v;
                else          Cf[idx] = v + res[idx];
            }
        }
    }
}

// ---------------- flash attention: one block per (seg, head) ----------------
// q[2048][4096] fp16, kv[16384][8192] fp16 (k cols 0..4095, v cols 4096..8191)
__global__ __launch_bounds__(256) void attn_kernel(const h16* __restrict__ q,
                                                   const h16* __restrict__ kv,
                                                   h16* __restrict__ o) {
    const int h = blockIdx.x;   // 0..31
    const int s = blockIdx.y;   // 0..31
    const int t = threadIdx.x;
    const int lane = t & 63, w = t >> 6;
    const int row16 = lane & 15, quad = lane >> 4;

    __shared__ h16 kls[32][HDIM + 8];      // [kcol][hd]
    __shared__ h16 vls[HDIM][32 + 8];      // [hd][kcol] (transposed)
    __shared__ h16 pls[4][16][32 + 8];     // per-wave P tile

    // q A-fragments: A[m=lane&15][k=quad*8+j], wave w owns q-rows w*16..w*16+15
    f16x8 qf[4];
    {
        const long qrow = (long)(s * RQ + w * 16 + row16) * DMODEL + h * HDIM;
#pragma unroll
        for (int f = 0; f < 4; f++) qf[f] = *(const f16x8*)&q[qrow + f * 32 + quad * 8];
    }
    const float sc = 0.08838834764831845f;  // 1/sqrt(128)
    f32x4 oacc[8] = {};
    float m_i[4], l_i[4];
#pragma unroll
    for (int r = 0; r < 4; r++) { m_i[r] = -1e30f; l_i[r] = 0.f; }

    const long kvbase = (long)s * LCTX * 8192 + h * HDIM;

    for (int kc = 0; kc < LCTX; kc += 32) {
        // stage k chunk [32][128] natural; v chunk transposed to [128][32]
#pragma unroll
        for (int p = 0; p < 2; p++) {
            int u = t + p * 256;
            int r = u >> 4;            // 0..31
            int c8 = (u & 15) * 8;     // 0..120
            *(uint4*)&kls[r][c8] = *(const uint4*)&kv[kvbase + (long)(kc + r) * 8192 + c8];
            f16x8 vv = *(const f16x8*)&kv[kvbase + 4096 + (long)(kc + r) * 8192 + c8];
#pragma unroll
            for (int j = 0; j < 8; j++) vls[c8 + j][r] = vv[j];
        }
        __syncthreads();

        // S = q @ k^T : two 16-col tiles, K=128 in 4 MFMA steps each
        f32x4 st[2] = {};
#pragma unroll
        for (int ct = 0; ct < 2; ct++)
#pragma unroll
            for (int f = 0; f < 4; f++) {
                f16x8 bk = *(const f16x8*)&kls[ct * 16 + row16][f * 32 + quad * 8];
                st[ct] = __builtin_amdgcn_mfma_f32_16x16x32_f16(qf[f], bk, st[ct], 0, 0, 0);
            }

        // online softmax; C layout: row = quad*4+r, col = lane&15
#pragma unroll
        for (int r = 0; r < 4; r++) {
            float s0 = st[0][r] * sc, s1 = st[1][r] * sc;
            float mx = fmaxf(s0, s1);
#pragma unroll
            for (int d = 1; d < 16; d <<= 1) mx = fmaxf(mx, __shfl_xor(mx, d, 64));
            float mn = fmaxf(m_i[r], mx);
            float al = __expf(m_i[r] - mn);
            float p0 = __expf(s0 - mn), p1 = __expf(s1 - mn);
            float ps = p0 + p1;
#pragma unroll
            for (int d = 1; d < 16; d <<= 1) ps += __shfl_xor(ps, d, 64);
            l_i[r] = l_i[r] * al + ps;
            m_i[r] = mn;
#pragma unroll
            for (int ht = 0; ht < 8; ht++) oacc[ht][r] *= al;
            pls[w][quad * 4 + r][row16]      = (h16)p0;
            pls[w][quad * 4 + r][16 + row16] = (h16)p1;
        }
        // P (C layout) -> A layout via per-wave LDS round-trip
        f16x8 pa = *(const f16x8*)&pls[w][row16][quad * 8];
#pragma unroll
        for (int ht = 0; ht < 8; ht++) {
            f16x8 bv = *(const f16x8*)&vls[ht * 16 + row16][quad * 8];
            oacc[ht] = __builtin_amdgcn_mfma_f32_16x16x32_f16(pa, bv, oacc[ht], 0, 0, 0);
        }
        __syncthreads();
    }
    // finalize: divide by l, store fp16
#pragma unroll
    for (int r = 0; r < 4; r++) {
        float inv = 1.0f / l_i[r];
        long orow = (long)(s * RQ + w * 16 + quad * 4 + r) * DMODEL + h * HDIM;
#pragma unroll
        for (int ht = 0; ht < 8; ht++) o[orow + ht * 16 + row16] = (h16)(oacc[ht][r] * inv);
    }
}

// ---------------- final rmsnorm ----------------
__global__ __launch_bounds__(256) void final_rms_kernel(const float* __restrict__ tmp,
                                                        const float* __restrict__ w,
                                                        float* __restrict__ out) {
    const int row = blockIdx.x;
    const int t = threadIdx.x;
    float v[16];
    float ss = 0.f;
#pragma unroll
    for (int i = 0; i < 16; i++) {
        v[i] = tmp[(long)row * DMODEL + t + i * 256];
        ss += v[i] * v[i];
    }
#pragma unroll
    for (int d = 1; d < 64; d <<= 1) ss += __shfl_xor(ss, d, 64);
    __shared__ float red[4];
    if ((t & 63) == 0) red[t >> 6] = ss;
    __syncthreads();
    float tot = red[0] + red[1] + red[2] + red[3];
    float scale = rsqrtf(tot / (float)DMODEL + 1e-5f);
#pragma unroll
    for (int i = 0; i < 16; i++) {
        int col = t + i * 256;
        out[(long)row * DMODEL + col] = v[i] * scale * w[col];
    }
}

extern "C" void kernel_launch(void* const* d_in, const int* in_sizes, int n_in,
                              void* d_out, int out_size, void* d_ws, size_t ws_size,
                              hipStream_t stream) {
    const float* x      = (const float*)d_in[0];  // [16384][4096]
    const float* anw    = (const float*)d_in[1];  // [4096]
    const float* wq     = (const float*)d_in[2];  // [4096][4096]
    const float* wkv    = (const float*)d_in[3];  // [4096][8192]
    const float* wo     = (const float*)d_in[4];  // [4096][4096]
    const float* onw    = (const float*)d_in[5];  // [4096]
    float* out          = (float*)d_out;          // [2048][4096]

    // workspace carve-up
    size_t off = 0;
    auto carve = [&](size_t bytes) {
        void* p = (char*)d_ws + off;
        off += (bytes + 255) & ~(size_t)255;
        return p;
    };
    h16*   xh      = (h16*)  carve((size_t)16384 * 4096 * 2);   // x fp16
    h16*   wqT     = (h16*)  carve((size_t)4096 * 4096 * 2);    // wq^T
    h16*   wkvT    = (h16*)  carve((size_t)8192 * 4096 * 2);    // wkv^T
    h16*   woT     = (h16*)  carve((size_t)4096 * 4096 * 2);    // wo^T
    float* queries = (float*)carve((size_t)2048 * 4096 * 4);
    h16*   qn      = (h16*)  carve((size_t)2048 * 4096 * 2);
    h16*   qh      = (h16*)  carve((size_t)2048 * 4096 * 2);
    h16*   kvh     = (h16*)  carve((size_t)16384 * 8192 * 2);
    h16*   oh      = (h16*)  carve((size_t)2048 * 4096 * 2);
    float* tmp     = (float*)xh;  // alias: x fp16 dead after kv GEMM

    // 1. casts / transposes
    cast_f16_kernel<<<(16384L * 4096 / 4) / 256, 256, 0, stream>>>(x, xh);
    transpose_cast_kernel<<<dim3(4096 / 32, 4096 / 32), 256, 0, stream>>>(wq, wqT, 4096, 4096);
    transpose_cast_kernel<<<dim3(8192 / 32, 4096 / 32), 256, 0, stream>>>(wkv, wkvT, 4096, 8192);
    transpose_cast_kernel<<<dim3(4096 / 32, 4096 / 32), 256, 0, stream>>>(wo, woT, 4096, 4096);

    // 2. pool + attention rmsnorm
    pool_rms_kernel<<<2048, 256, 0, stream>>>(x, anw, queries, qn);

    // 3. q = qn @ wq        (M=2048, N=4096, K=4096)
    gemm_bt_kernel<<<dim3(4096 / 128, 2048 / 128), 256, 0, stream>>>(
        qn, wqT, qh, nullptr, nullptr, 2048, 4096, 4096, 0);

    // 4. kv = x @ wkv       (M=16384, N=8192, K=4096)  -- the big one
    gemm_bt_kernel<<<dim3(8192 / 128, 16384 / 128), 256, 0, stream>>>(
        xh, wkvT, kvh, nullptr, nullptr, 16384, 8192, 4096, 0);

    // 5. attention per (seg, head)
    attn_kernel<<<dim3(NH, SEGS), 256, 0, stream>>>(qh, kvh, oh);

    // 6. out = o @ wo + queries   (M=2048, N=4096, K=4096), fp32 + residual
    gemm_bt_kernel<<<dim3(4096 / 128, 2048 / 128), 256, 0, stream>>>(
        oh, woT, nullptr, tmp, queries, 2048, 4096, 4096, 1);

    // 7. final rmsnorm -> d_out
    final_rms_kernel<<<2048, 256, 0, stream>>>(tmp, onw, out);
}